// Round 1
// 74.589 us; speedup vs baseline: 1.0042x; 1.0042x over previous
//
#include <hip/hip_runtime.h>

// QuantumConv2d on MI355X — R3: packed-fp32 (v_pk_fma_f32) over the two
// patches each thread owns. Patch A lives in .x, patch B in .y of every
// <2 x float> value; all phase/butterfly/probability arithmetic is then
// 2-wide packed with zero cross-half traffic. Transcendentals (v_sin/v_cos)
// remain scalar (no packed variant): 64+8 per thread.
//
// Thread t: b = t>>13, v = (t>>6)&127, up = (t&63)*2  -> patches (up,v),(up+1,v)
// Loads: float4 from rows 2v and 2v+1 at col 4*(t&63).
// Stores: two adjacent float4 = 32B contiguous per thread, coalesced.
//
// Per patch: 16 diagonal phasors exp(-i*phi_k) with
//   phi_k = 0.25 t^2 + 0.5 t - 0.25*sum(x^2)  (evaluated in revolutions),
//   t = sum_q (+-)x_q (LSB-first signs),
// then 4 RX butterfly stages (c,s from weights, shared by both patches),
// then CNOT-ring == GF(2) bit permutation -> parity-masked |y|^2 sums.

#define INV2PI 0.15915494309189535f

typedef __attribute__((ext_vector_type(2))) float f2;

__device__ __forceinline__ f2 splat(float v) { f2 r; r.x = v; r.y = v; return r; }

__global__ __launch_bounds__(256) void qconv2d_kernel(
    const float* __restrict__ x,   // [64, 256, 256]
    const float* __restrict__ w,   // [4]
    float* __restrict__ out)       // [64, 128, 128, 4]
{
    const int t = blockIdx.x * 256 + threadIdx.x;   // 2 patches per thread
    const int uh = t & 63;              // u-pair index: patches 2*uh, 2*uh+1
    const int v  = (t >> 6) & 127;
    const int b  = t >> 13;

    // rows 2v, 2v+1; cols 4*uh .. 4*uh+3
    const float* base = x + ((size_t)b << 16) + ((size_t)(v << 1) << 8) + (uh << 2);
    const float4 r0 = *(const float4*)(base);
    const float4 r1 = *(const float4*)(base + 256);

    float cw[4], sw[4];
#pragma unroll
    for (int q = 0; q < 4; ++q) {
        const float r = w[q] * (0.5f * INV2PI);
        sw[q] = __builtin_amdgcn_sinf(r);
        cw[q] = __builtin_amdgcn_cosf(r);
    }

    // pack: .x = patch u=2uh (r0.x,r0.y,r1.x,r1.y), .y = patch u=2uh+1
    f2 x0; x0.x = r0.x; x0.y = r0.z;
    f2 x1; x1.x = r0.y; x1.y = r0.w;
    f2 x2; x2.x = r1.x; x2.y = r1.z;
    f2 x3; x3.x = r1.y; x3.y = r1.w;

    const f2 a0 = x0 + x1, a1 = x0 - x1;
    const f2 b0 = x2 + x3, b1 = x2 - x3;
    const f2 ss = x0*x0 + x1*x1 + x2*x2 + x3*x3;
    const f2 cbase = splat(-0.25f * INV2PI) * ss;
    const f2 cA = splat(0.25f * INV2PI);
    const f2 cB = splat(0.5f * INV2PI);

    const f2 lo0 = -a0, lo1 = a1, lo2 = -a1, lo3 = a0;
    const f2 hi0 = -b0, hi1 = b1, hi2 = -b1, hi3 = b0;

    f2 yr[16], yi[16];
#pragma unroll
    for (int k = 0; k < 16; ++k) {
        const f2 lo = (k & 1) ? ((k & 2) ? lo3 : lo1) : ((k & 2) ? lo2 : lo0);
        const f2 hi = (k & 4) ? ((k & 8) ? hi3 : hi1) : ((k & 8) ? hi2 : hi0);
        const f2 tt  = lo + hi;
        const f2 rev = __builtin_elementwise_fma(
            tt, __builtin_elementwise_fma(cA, tt, cB), cbase);
        f2 c, s;
        c.x = __builtin_amdgcn_cosf(rev.x);
        c.y = __builtin_amdgcn_cosf(rev.y);
        s.x = __builtin_amdgcn_sinf(rev.x);
        s.y = __builtin_amdgcn_sinf(rev.y);
        yr[k] = c;
        yi[k] = -s;
    }

#pragma unroll
    for (int q = 0; q < 4; ++q) {
        const f2 c  = splat(cw[q]);
        const f2 s  = splat(sw[q]);
        const f2 ns = splat(-sw[q]);   // hoisted negation: no runtime fneg in loop
#pragma unroll
        for (int k0 = 0; k0 < 16; ++k0) {
            if (k0 & (1 << q)) continue;
            const int k1 = k0 | (1 << q);
            const f2 ar = yr[k0], ai = yi[k0];
            const f2 br = yr[k1], bi = yi[k1];
            yr[k0] = __builtin_elementwise_fma(c, ar, s  * bi);
            yi[k0] = __builtin_elementwise_fma(c, ai, ns * br);
            yr[k1] = __builtin_elementwise_fma(c, br, s  * ai);
            yi[k1] = __builtin_elementwise_fma(c, bi, ns * ar);
        }
    }

    f2 o0 = splat(0.f), o1 = o0, o2 = o0, o3 = o0;
#pragma unroll
    for (int j = 0; j < 16; ++j) {
        const f2 p = __builtin_elementwise_fma(yr[j], yr[j], yi[j] * yi[j]);
        const int q0 = j & 1, q1 = (j >> 1) & 1, q2 = (j >> 2) & 1, q3 = (j >> 3) & 1;
        if (q0 ^ q1 ^ q2 ^ q3) o0 += p;
        if (q0 ^ q1 ^ q2)      o1 += p;
        if (q0 ^ q1)           o2 += p;
        if (q1 ^ q2 ^ q3)      o3 += p;
    }

    const f2 sc = splat(0.0625f);
    o0 *= sc; o1 *= sc; o2 *= sc; o3 *= sc;

    float4 resA, resB;
    resA.x = o0.x;  resB.x = o0.y;
    resA.y = o1.x;  resB.y = o1.y;
    resA.z = o2.x;  resB.z = o2.y;
    resA.w = o3.x;  resB.w = o3.y;

    // out[b, v, u, 0..3]; u = 2*uh and 2*uh+1 -> 32B contiguous
    float4* o = (float4*)(out + (((size_t)t) << 3));
    o[0] = resA;
    o[1] = resB;
}

extern "C" void kernel_launch(void* const* d_in, const int* in_sizes, int n_in,
                              void* d_out, int out_size, void* d_ws, size_t ws_size,
                              hipStream_t stream) {
    const float* x = (const float*)d_in[0];   // [64,256,256] fp32
    const float* w = (const float*)d_in[1];   // [2,2] fp32
    float* out = (float*)d_out;               // [64,128,128,4] fp32

    const int total = 64 * 128 * 64;          // two patches per thread
    qconv2d_kernel<<<dim3(total / 256), dim3(256), 0, stream>>>(x, w, out);
}